// Round 1
// baseline (4132.357 us; speedup 1.0000x reference)
//
#include <hip/hip_runtime.h>
#include <cfloat>

#define NOBS  256
#define NY    50
#define NX    30
#define NITER 400
#define LRATE 0.05f
#define STR   51   // ep row stride in LDS: odd -> conflict-free column reads; col 50 = ones (for gc)

__global__ __launch_bounds__(256) void dro_kernel(
    const float* __restrict__ X, const float* __restrict__ Y,
    const float* __restrict__ W, const float* __restrict__ B,
    const float* __restrict__ DLT, const float* __restrict__ GMM,
    float* __restrict__ out)
{
  __shared__ __align__(16) float ep_l[NOBS * STR];  // 52224 B
  __shared__ __align__(16) float rr[NOBS];
  __shared__ __align__(16) float coef[NOBS];
  __shared__ __align__(16) float red[NOBS];
  __shared__ __align__(16) float zvp[64];           // z, lanes 50..63 = 0
  __shared__ float yh[NY];
  __shared__ float wmax[4];
  __shared__ int   wcnt[4];
  __shared__ float cbuf;

  const int tid  = threadIdx.x;
  const int t    = blockIdx.x;
  const int lane = tid & 63;
  const int wid  = tid >> 6;

  const float delta = DLT[0];
  const float gamma = GMM[0];
  const float a     = fminf(delta * 0.5f, 255.0f / 256.0f);
  const float a256  = a * 256.0f;

  // ---- init: thread tid computes ep row tid; block t also emits Y_hat row t ----
  float xr[NX];
  #pragma unroll
  for (int k = 0; k < NX; ++k) xr[k] = X[tid * NX + k];

  float er[52];
  for (int j = 0; j < NY; ++j) {
    float acc = B[j];
    #pragma unroll
    for (int k = 0; k < NX; ++k) acc = fmaf(xr[k], W[j * NX + k], acc);
    float e = Y[tid * NY + j] - acc;
    er[j] = e;
    ep_l[tid * STR + j] = e;
    if (tid == t) { yh[j] = acc; out[NOBS * NY + t * NY + j] = acc; }
  }
  er[50] = 0.0f; er[51] = 0.0f;
  ep_l[tid * STR + NY] = 1.0f;                       // ones column -> gc
  if (tid < 64) zvp[tid] = (tid < NY) ? (float)(1.0 / 50.0) : 0.0f;
  if (tid == 0) cbuf = 0.0f;
  __syncthreads();

  #pragma unroll 1
  for (int it = 0; it < NITER; ++it) {
    // ---- forward: u_i = ep_i . z - c ; r_i = u_i^2 ----
    const float c_cur = cbuf;
    float u = 0.0f;
    #pragma unroll
    for (int q = 0; q < 13; ++q) {                   // z[50],z[51]=0 pad
      float4 zq = *(const float4*)&zvp[4 * q];
      u = fmaf(er[4*q+0], zq.x, u);
      u = fmaf(er[4*q+1], zq.y, u);
      u = fmaf(er[4*q+2], zq.z, u);
      u = fmaf(er[4*q+3], zq.w, u);
    }
    u -= c_cur;
    const float r = u * u;
    rr[tid] = r;

    float m = r;                                     // wave max
    #pragma unroll
    for (int off = 32; off >= 1; off >>= 1) m = fmaxf(m, __shfl_xor(m, off, 64));
    if (lane == 0) wmax[wid] = m;
    __syncthreads();                                 // B1: rr, wmax visible

    const float mx = fmaxf(fmaxf(wmax[0], wmax[1]), fmaxf(wmax[2], wmax[3]));
    const bool ismax = (r == mx);
    const int cw = __popcll(__ballot(ismax));
    if (lane == 0) wcnt[wid] = cw;

    // stable ascending rank of r among all 256 (exact; overlaps B2)
    int cnt = 0;
    #pragma unroll 4
    for (int k4 = 0; k4 < NOBS; k4 += 4) {
      float4 rq = *(const float4*)&rr[k4];           // broadcast read
      cnt += ((rq.x < r) || (rq.x == r && (k4+0) < tid)) ? 1 : 0;
      cnt += ((rq.y < r) || (rq.y == r && (k4+1) < tid)) ? 1 : 0;
      cnt += ((rq.z < r) || (rq.z == r && (k4+2) < tid)) ? 1 : 0;
      cnt += ((rq.w < r) || (rq.w == r && (k4+3) < tid)) ? 1 : 0;
    }
    __syncthreads();                                 // B2: wcnt visible
    const int cm = wcnt[0] + wcnt[1] + wcnt[2] + wcnt[3];

    // g_i = (1/N) clamp(rank+1-aN, 0, 1) + a*[tied max]/#ties
    const float gfac = fminf(fmaxf((float)cnt + 1.0f - a256, 0.0f), 1.0f) * (1.0f / 256.0f);
    const float g = gfac + (ismax ? (a / (float)cm) : 0.0f);
    coef[tid] = 2.0f * u * g;
    __syncthreads();                                 // B3: coef visible

    // ---- backward: per-wave partial column sums of coef^T @ ep (cols 0..50) ----
    if (lane < 51) {
      float p = 0.0f;
      const float*  eb = &ep_l[(wid * 64) * STR + lane];
      const float4* cb = (const float4*)&coef[wid * 64];
      #pragma unroll
      for (int ii = 0; ii < 16; ++ii) {
        float4 cq = cb[ii];                          // broadcast read
        p = fmaf(cq.x, eb[(4*ii+0) * STR], p);
        p = fmaf(cq.y, eb[(4*ii+1) * STR], p);
        p = fmaf(cq.z, eb[(4*ii+2) * STR], p);
        p = fmaf(cq.w, eb[(4*ii+3) * STR], p);
      }
      red[tid] = p;
    }
    __syncthreads();                                 // B4: red visible

    // ---- step + exact simplex projection, all inside wave 0 ----
    if (tid < 64) {
      const int l = tid;
      float s4 = 0.0f, v = 0.0f;
      if (l < 51) s4 = red[l] + red[64 + l] + red[128 + l] + red[192 + l];
      if (l < NY) {
        const float gz = s4 - gamma * yh[l];
        v = zvp[l] - LRATE * gz;
      }
      if (l == NY) cbuf = c_cur + LRATE * s4;        // gc = -s4

      float sv = (l < NY) ? v : FLT_MAX;             // ascending bitonic, pads on top
      #pragma unroll
      for (int k = 2; k <= 64; k <<= 1) {
        #pragma unroll
        for (int j = k >> 1; j > 0; j >>= 1) {
          const float o  = __shfl_xor(sv, j, 64);
          const bool  up = ((l & k) == 0);
          const bool  sm = ((l & j) == 0);
          const float lo = fminf(sv, o), hi = fmaxf(sv, o);
          sv = (up == sm) ? lo : hi;
        }
      }
      int src = 49 - l; if (src < 0) src = 0;        // descending view
      float ud = __shfl(sv, src, 64);
      if (l >= NY) ud = 0.0f;
      float cs = ud;                                 // inclusive scan
      #pragma unroll
      for (int off = 1; off < 64; off <<= 1) {
        const float tt = __shfl_up(cs, off, 64);
        if (l >= off) cs += tt;
      }
      cs -= 1.0f;
      const bool cond = (l < NY) && ((ud - cs / (float)(l + 1)) > 0.0f);
      const unsigned long long bb = __ballot(cond);
      const int rho = __popcll(bb);                  // >= 1 always
      const float csr = __shfl(cs, rho - 1, 64);
      const float tau = csr / (float)rho;
      if (l < NY) zvp[l] = fmaxf(v - tau, 0.0f);
    }
    __syncthreads();                                 // B5: z, c visible
  }

  if (tid < NY) out[t * NY + tid] = zvp[tid];
}

extern "C" void kernel_launch(void* const* d_in, const int* in_sizes, int n_in,
                              void* d_out, int out_size, void* d_ws, size_t ws_size,
                              hipStream_t stream) {
  (void)in_sizes; (void)n_in; (void)d_ws; (void)ws_size; (void)out_size;
  const float* X   = (const float*)d_in[0];
  const float* Y   = (const float*)d_in[1];
  const float* W   = (const float*)d_in[2];
  const float* B   = (const float*)d_in[3];
  const float* DLT = (const float*)d_in[4];
  const float* GMM = (const float*)d_in[5];
  float* out = (float*)d_out;
  hipLaunchKernelGGL(dro_kernel, dim3(NOBS), dim3(NOBS), 0, stream,
                     X, Y, W, B, DLT, GMM, out);
}

// Round 2
// 2585.657 us; speedup vs baseline: 1.5982x; 1.5982x over previous
//
#include <hip/hip_runtime.h>
#include <cfloat>
#include <math.h>

#define NOBS   256
#define NY     50
#define NX     30
#define NITER  400
#define LRATE  0.05f
#define CSTR   260     // ep_t column stride (floats): 16B-aligned rows, conflict-free b128 column reads
#define THRANK 40      // persisted threshold tracks the rank-40 element (aN <= 25.6 always)

__device__ __forceinline__ float rl_f(float x, int k) {
  // v_readlane: SGPR broadcast, no DS-pipe traffic (unlike __shfl -> ds_bpermute)
  return __int_as_float(__builtin_amdgcn_readlane(__float_as_int(x), k));
}

// wave64 max-reduce via DPP: row_shr 1,2,4,8 then row_bcast:15, row_bcast:31 -> lane 63 has max.
// bound_ctrl=false + old=x keeps invalid lanes at x (identity for max).
#define DPP_MAXSTEP(x, ctrl)                                                       \
  x = fmaxf(x, __int_as_float(__builtin_amdgcn_update_dpp(                         \
        __float_as_int(x), __float_as_int(x), (ctrl), 0xF, 0xF, false)))

__global__ __launch_bounds__(256) void dro_kernel(
    const float* __restrict__ X, const float* __restrict__ Y,
    const float* __restrict__ W, const float* __restrict__ B,
    const float* __restrict__ DLT, const float* __restrict__ GMM,
    float* __restrict__ out)
{
  __shared__ __align__(16) float ep_t[51 * CSTR];              // 53040 B, column-major (+ ones col)
  __shared__ __align__(16) unsigned long long rrk[NOBS];       // stable sort keys (fallback scan)
  __shared__ __align__(16) unsigned long long ckey[264];       // compacted candidate keys + pads
  __shared__ __align__(16) float red[NOBS];                    // per-wave column partials
  __shared__ __align__(16) float wmax4[4];
  __shared__ int   wcnt[4];
  __shared__ int   ccnt[4];
  __shared__ float yh_l[NY];
  __shared__ float sh_theta;

  const int tid  = threadIdx.x;
  const int t    = blockIdx.x;
  const int lane = tid & 63;
  const int wid  = tid >> 6;

  const float delta = DLT[0];
  const float gamma = GMM[0];
  const float a     = fminf(delta * 0.5f, 255.0f / 256.0f);
  const float a256  = a * 256.0f;

  // ---- init: thread tid owns obs row tid; block t also emits Y_hat row t ----
  float xr[NX];
  #pragma unroll
  for (int k = 0; k < NX; ++k) xr[k] = X[tid * NX + k];

  float er[NY];
  #pragma unroll 2
  for (int j = 0; j < NY; ++j) {
    float acc = B[j];                                  // W/B indices wave-uniform -> s_load
    #pragma unroll
    for (int k = 0; k < NX; ++k) acc = fmaf(xr[k], W[j * NX + k], acc);
    float e = Y[tid * NY + j] - acc;
    er[j] = e;
    ep_t[j * CSTR + tid] = e;                          // column-major
    if (tid == t) { yh_l[j] = acc; out[NOBS * NY + t * NY + j] = acc; }
  }
  ep_t[NY * CSTR + tid] = 1.0f;                        // ones column -> c gradient
  if (tid == 0) sh_theta = FLT_MAX;                    // iter 0: everyone is a candidate (exact)
  __syncthreads();

  const float yhl = (lane < NY) ? yh_l[lane] : 0.0f;   // per-lane register copy
  float zv = (lane < NY) ? (1.0f / NY) : 0.0f;         // z distributed one entry/lane, replicated per wave
  float cc = 0.0f;                                     // c, wave-uniform, replicated per wave

  #pragma unroll 1
  for (int it = 0; it < NITER; ++it) {
    // ---- phase 1: forward u = ep_row . z - c (z via readlane, zero LDS) ----
    float u0 = 0.f, u1 = 0.f, u2 = 0.f, u3 = 0.f;
    #pragma unroll
    for (int k = 0; k < 48; k += 4) {
      u0 = fmaf(er[k + 0], rl_f(zv, k + 0), u0);
      u1 = fmaf(er[k + 1], rl_f(zv, k + 1), u1);
      u2 = fmaf(er[k + 2], rl_f(zv, k + 2), u2);
      u3 = fmaf(er[k + 3], rl_f(zv, k + 3), u3);
    }
    u0 = fmaf(er[48], rl_f(zv, 48), u0);
    u1 = fmaf(er[49], rl_f(zv, 49), u1);
    const float u = (u0 + u2) + (u1 + u3) - cc;
    const float r = u * u;

    // stable sort key: r>=0 so float bits are order-isomorphic; low 32 = index (stable ties)
    const unsigned long long key =
        ((unsigned long long)(unsigned)__float_as_int(r) << 32) | (unsigned)tid;
    rrk[tid] = key;

    float m = r;                                       // wave max via DPP (no DS ops)
    DPP_MAXSTEP(m, 0x111); DPP_MAXSTEP(m, 0x112);      // row_shr:1, row_shr:2
    DPP_MAXSTEP(m, 0x114); DPP_MAXSTEP(m, 0x118);      // row_shr:4, row_shr:8
    DPP_MAXSTEP(m, 0x142); DPP_MAXSTEP(m, 0x143);      // row_bcast:15, row_bcast:31
    if (lane == 63) wmax4[wid] = m;

    const float theta = sh_theta;                      // written before prev B3 -> safe read
    const bool  cond  = (r < theta);
    const unsigned long long cmask = __ballot(cond);
    const int cpos = __popcll(cmask & ((1ull << lane) - 1ull));
    if (lane == 0) ccnt[wid] = __popcll(cmask);
    __syncthreads();                                   // B1: rrk, wmax4, ccnt

    // ---- phase 2: max ties + candidate compaction ----
    const float mx = fmaxf(fmaxf(wmax4[0], wmax4[1]), fmaxf(wmax4[2], wmax4[3]));
    const bool ismax = (r == mx);
    const unsigned long long mmask = __ballot(ismax);
    if (lane == 0) wcnt[wid] = __popcll(mmask);

    const int c0 = ccnt[0], c1 = ccnt[1], c2 = ccnt[2], c3 = ccnt[3];
    const int coff = (wid > 0 ? c0 : 0) + (wid > 1 ? c1 : 0) + (wid > 2 ? c2 : 0);
    const int C = c0 + c1 + c2 + c3;
    if (cond) ckey[coff + cpos] = key;
    if (tid < 4) ckey[C + tid] = ~0ull;                // pads (never count: max key)
    __syncthreads();                                   // B2: wcnt, ckey

    // ---- phase 3: exact stable rank (candidates only, unless invalid) ----
    const int  cm    = wcnt[0] + wcnt[1] + wcnt[2] + wcnt[3];
    const bool valid = ((float)C >= a256);             // all non-candidates have rank >= C >= aN
    int cnt;
    if (valid) {
      cnt = 300;                                       // non-candidate: g = 1/N branchlessly
      if (cond) {
        int acc_c = 0;
        const int Cr = (C + 1) & ~1;
        for (int j = 0; j < Cr; j += 2) {
          ulonglong2 kk = *(const ulonglong2*)&ckey[j];
          acc_c += (kk.x < key) ? 1 : 0;
          acc_c += (kk.y < key) ? 1 : 0;
        }
        cnt = acc_c;                                   // == exact global stable rank
      }
    } else {                                           // rare (iter 0 + drift); exact full scan
      int acc_c = 0;
      #pragma unroll 4
      for (int j = 0; j < NOBS; j += 2) {
        ulonglong2 kk = *(const ulonglong2*)&rrk[j];
        acc_c += (kk.x < key) ? 1 : 0;
        acc_c += (kk.y < key) ? 1 : 0;
      }
      cnt = acc_c;
    }
    // g_i = (1/N) clamp(rank+1-aN, 0, 1) + a*[tied max]/#ties
    const float gfac  = fminf(fmaxf((float)cnt + 1.0f - a256, 0.0f), 1.0f) * (1.0f / 256.0f);
    const float g     = gfac + (ismax ? (a / (float)cm) : 0.0f);
    const float coefv = 2.0f * u * g;
    if (cnt == THRANK) sh_theta = r;                   // unique rank -> single writer

    // ---- phase 4: backward. coef via readlane (own wave's lanes), ep columns via b128 ----
    const int col = (lane < 51) ? lane : 50;           // clamp: lanes 51..63 harmless dupes
    const float4* eb = (const float4*)&ep_t[col * CSTR + wid * 64];
    float p0 = 0.f, p1 = 0.f, p2 = 0.f, p3 = 0.f;
    #pragma unroll
    for (int q = 0; q < 16; ++q) {
      float4 e4 = eb[q];
      p0 = fmaf(rl_f(coefv, 4 * q + 0), e4.x, p0);
      p1 = fmaf(rl_f(coefv, 4 * q + 1), e4.y, p1);
      p2 = fmaf(rl_f(coefv, 4 * q + 2), e4.z, p2);
      p3 = fmaf(rl_f(coefv, 4 * q + 3), e4.w, p3);
    }
    red[wid * 64 + lane] = (p0 + p2) + (p1 + p3);
    __syncthreads();                                   // B3: red

    // ---- phase 5: gradient step + simplex projection, replicated in every wave ----
    const float s4 = red[lane] + red[64 + lane] + red[128 + lane] + red[192 + lane];
    cc = cc + LRATE * rl_f(s4, 50);                    // gc = -sum(coef); col 50 = ones
    const float gz = s4 - gamma * yhl;
    const float v  = zv - LRATE * gz;

    // counting-method projection: ahead = descending stable position, csum = sum of "ahead" values
    int ahead = 0; float cs0 = 0.f, cs1 = 0.f;
    #pragma unroll
    for (int k = 0; k < 50; k += 2) {
      const float vk0 = rl_f(v, k);
      const float vk1 = rl_f(v, k + 1);
      const bool a0 = (vk0 > v) || (vk0 == v && (k    ) > lane);
      const bool a1 = (vk1 > v) || (vk1 == v && (k + 1) > lane);
      ahead += (a0 ? 1 : 0) + (a1 ? 1 : 0);
      cs0 += a0 ? vk0 : 0.0f;
      cs1 += a1 ? vk1 : 0.0f;
    }
    const float css = (cs0 + cs1) + v - 1.0f;          // cumsum at my descending pos, minus 1
    const bool pc = (lane < NY) && (v - css / (float)(ahead + 1) > 0.0f);
    const int rho = __popcll(__ballot(pc));            // >= 1 always
    const unsigned long long bsel = __ballot((lane < NY) && (ahead == rho - 1));
    const int srcl = __ffsll(bsel) - 1;
    const float tau =
        __int_as_float(__builtin_amdgcn_readlane(__float_as_int(css), srcl)) / (float)rho;
    zv = (lane < NY) ? fmaxf(v - tau, 0.0f) : 0.0f;
  }

  if (wid == 0 && lane < NY) out[t * NY + lane] = zv;
}

extern "C" void kernel_launch(void* const* d_in, const int* in_sizes, int n_in,
                              void* d_out, int out_size, void* d_ws, size_t ws_size,
                              hipStream_t stream) {
  (void)in_sizes; (void)n_in; (void)d_ws; (void)ws_size; (void)out_size;
  const float* X   = (const float*)d_in[0];
  const float* Y   = (const float*)d_in[1];
  const float* W   = (const float*)d_in[2];
  const float* B   = (const float*)d_in[3];
  const float* DLT = (const float*)d_in[4];
  const float* GMM = (const float*)d_in[5];
  float* out = (float*)d_out;
  hipLaunchKernelGGL(dro_kernel, dim3(NOBS), dim3(NOBS), 0, stream,
                     X, Y, W, B, DLT, GMM, out);
}